// Round 10
// baseline (162.176 us; speedup 1.0000x reference)
//
#include <hip/hip_runtime.h>
#include <math.h>

#define NH 16
#define HD 64
#define SEQ 2048
#define BAT 2
#define EMB 1024
#define MTOT (BAT*SEQ)   // 4096
#define NTOT (3*EMB)     // 3072

typedef __attribute__((ext_vector_type(8))) short bf16x8;
typedef __attribute__((ext_vector_type(4))) float f32x4;

#define MFMA16(a,b,c) __builtin_amdgcn_mfma_f32_16x16x32_bf16(a,b,c,0,0,0)

__device__ inline short f2bf(float f) {
    union { float f; unsigned u; } x; x.f = f;
    unsigned r = (x.u + 0x7FFF + ((x.u >> 16) & 1)) >> 16;
    return (short)r;
}

// raw v_exp_f32 (inputs bounded to [-12,12]: no range/denorm handling needed)
__device__ inline float fast_exp2(float x) {
#if __has_builtin(__builtin_amdgcn_exp2f)
    return __builtin_amdgcn_exp2f(x);
#else
    float r; asm("v_exp_f32 %0, %1" : "=v"(r) : "v"(x)); return r;
#endif
}

// pack two f32 -> bf16x2 by truncation: single v_perm (P-weights; bias
// cancels in O/l ratio since l uses the same truncated P)
__device__ inline unsigned pack2bf_t(float a, float b) {
    union { float f; unsigned u; } x, y; x.f = a; y.f = b;
    return __builtin_amdgcn_perm(y.u, x.u, 0x07060302u);
}

typedef const __attribute__((address_space(1))) void* gp_t;
typedef __attribute__((address_space(3))) void* lp_t;
// async global->LDS, 16B/lane; LDS dest = wave-uniform base + lane*16
__device__ inline void gload16(const void* g, void* l) {
    __builtin_amdgcn_global_load_lds((gp_t)(uintptr_t)g, (lp_t)(uintptr_t)l, 16, 0, 0);
}

// ===========================================================================
// FRAGMENT-ORDER LAYOUTS (the round-10 change): all staged operands live in
// memory as 1KB blocks = one wave MFMA-fragment set, lane-contiguous:
//   block[lane][j] (j=0..7 bf16). So every global_load_lds reads a fully
//   contiguous 1KB (perfect coalescing) and every ds_read_b128 frag read is
//   a contiguous 1KB (provably bank-conflict-free). No XOR swizzles anywhere.
//
//   xb  A-frags: blk(S,kb)[lane] = x[S*16 + (lane&15)][kb*32 + (lane>>4)*8..]
//   wb  B-frags: same with concat-W row; blk idx = strip*32 + kb
//   qws Q B-frags: blk(bh,strip,ks)[lane] = Q[strip*16+l16][ks*32+quad*8..]
//   kws K A-frags: same shape as qws
//   vperm V B-frags: blk(bh,strip32,nt)[lane] = V[key(slot=quad*8+j)][nt*16+l16]
//     slot->token within 32-group: tok = (j&3) | ((j>>2)<<4) | (quad<<2)
// ===========================================================================

// ---------------------------------------------------------------------------
// Prep: f32 -> bf16 in fragment order. One 64-lane "virtual wave" per block.
// 14336 frag blocks total (xb 8192 | wb 6144).
// ---------------------------------------------------------------------------
__global__ __launch_bounds__(256) void prep_kernel(
    const float* __restrict__ x, const float* __restrict__ wq,
    const float* __restrict__ wk, const float* __restrict__ wv,
    short* __restrict__ xb, short* __restrict__ wb)
{
    const int g = blockIdx.x * 256 + threadIdx.x;
    const int bid = g >> 6, lane = g & 63;
    const int l16 = lane & 15, quad = lane >> 4;
    const float* src; short* dst;
    if (bid < 8192) {                         // xb: 256 strips x 32 kb
        const int S = bid >> 5, kb = bid & 31;
        src = x + (size_t)(S * 16 + l16) * EMB + kb * 32 + quad * 8;
        dst = xb + (size_t)bid * 512 + lane * 8;
    } else {                                  // wb: 192 strips x 32 kb
        const int wid = bid - 8192;
        const int mat = wid >> 11, within = wid & 2047;
        const int S = within >> 5, kb = within & 31;
        const float* w = (mat == 0) ? wq : (mat == 1) ? wk : wv;
        src = w + (size_t)(S * 16 + l16) * EMB + kb * 32 + quad * 8;
        dst = wb + (size_t)wid * 512 + lane * 8;
    }
    float4 a = *(const float4*)src, b2 = *(const float4*)(src + 4);
    union { int4 v; short s[8]; } o;
    o.s[0]=f2bf(a.x);  o.s[1]=f2bf(a.y);  o.s[2]=f2bf(a.z);  o.s[3]=f2bf(a.w);
    o.s[4]=f2bf(b2.x); o.s[5]=f2bf(b2.y); o.s[6]=f2bf(b2.z); o.s[7]=f2bf(b2.w);
    *(int4*)dst = o.v;
}

// ---------------------------------------------------------------------------
// Fused QKV GEMM: 128x128 tile, BK=64, double-buffered, fragment-order
// staging (contiguous 1KB gload16, contiguous conflict-free b128 frag reads).
// Epilogue through LDS T then fragment-order writes of qws/kws/vperm.
// ---------------------------------------------------------------------------
__global__ __launch_bounds__(256) void qkv_gemm_fast(
    const short* __restrict__ xb, const short* __restrict__ wb,
    short* __restrict__ qws, short* __restrict__ kws, short* __restrict__ vperm,
    const float* __restrict__ gptr)
{
    __shared__ short smem[2 * 16384];   // [buf][A 8K shorts | B 8K shorts]
    const int m0 = blockIdx.x * 128, n0 = blockIdx.y * 128;
    const int t = threadIdx.x, wave = t >> 6, lane = t & 63;
    const int quad = lane >> 4, l16 = lane & 15;
    const int wm = (wave & 1) * 64, wn = (wave >> 1) * 64;
    const int SA = m0 >> 4;          // first of 8 A strips
    const int SB = n0 >> 4;          // first of 8 B strips (concat-W)

    // frag read offsets (buffer-relative; strip i adds i*1024)
    int aoff[2], boff[2];
#pragma unroll
    for (int ks = 0; ks < 2; ++ks) {
        aoff[ks] = ((wave & 1) * 8 + ks) * 512 + lane * 8;
        boff[ks] = 8192 + ((wave >> 1) * 8 + ks) * 512 + lane * 8;
    }

    f32x4 acc[4][4] = {};

    // stage iter it into buffer p: wave stages strips {2w,2w+1} x kb {0,1}
    auto stageg = [&](int it, int p) {
        short* ls = smem + p * 16384;
        const int kb0 = it * 2;
#pragma unroll
        for (int s = 0; s < 2; ++s) {
            const int sg = wave * 2 + s;
#pragma unroll
            for (int kbl = 0; kbl < 2; ++kbl) {
                gload16(xb + ((size_t)(SA + sg) * 32 + kb0 + kbl) * 512 + lane * 8,
                        ls + (sg * 2 + kbl) * 512 + lane * 8);
                gload16(wb + ((size_t)(SB + sg) * 32 + kb0 + kbl) * 512 + lane * 8,
                        ls + 8192 + (sg * 2 + kbl) * 512 + lane * 8);
            }
        }
    };

    stageg(0, 0);
    __syncthreads();

    for (int it = 0; it < EMB / 64; ++it) {
        const int p = it & 1;
        if (it + 1 < EMB / 64) stageg(it + 1, p ^ 1);   // prefetch overlaps compute
        const short* base = smem + p * 16384;
#pragma unroll
        for (int ks = 0; ks < 2; ++ks) {
            bf16x8 af[4], bfr[4];
#pragma unroll
            for (int i = 0; i < 4; ++i) af[i]  = *(const bf16x8*)(base + aoff[ks] + i * 1024);
#pragma unroll
            for (int i = 0; i < 4; ++i) bfr[i] = *(const bf16x8*)(base + boff[ks] + i * 1024);
#pragma unroll
            for (int mf = 0; mf < 4; ++mf)
#pragma unroll
                for (int nf = 0; nf < 4; ++nf)
                    acc[mf][nf] = MFMA16(af[mf], bfr[nf], acc[mf][nf]);
        }
        __syncthreads();
    }

    // ---- epilogue (LDS transpose tile T, then fragment-order stores) ----
    short* T = smem;   // 128 x 128 bf16, 16B-granule XOR col swizzle (LDS only)
    const int mat = n0 >> 10;   // 0=Q,1=K,2=V (block-uniform)

    if (mat < 2) {
        const float scale = (mat == 0) ? gptr[0] * 1.4426950408889634f : 1.0f;
        float inv[4][4];
#pragma unroll
        for (int mf = 0; mf < 4; ++mf)
#pragma unroll
            for (int reg = 0; reg < 4; ++reg) {
                float ss = 0.f;
#pragma unroll
                for (int nf = 0; nf < 4; ++nf) { float v = acc[mf][nf][reg]; ss += v * v; }
                ss += __shfl_xor(ss, 1, 16);
                ss += __shfl_xor(ss, 2, 16);
                ss += __shfl_xor(ss, 4, 16);
                ss += __shfl_xor(ss, 8, 16);
                inv[mf][reg] = scale / fmaxf(sqrtf(ss), 1e-12f);
            }
#pragma unroll
        for (int mf = 0; mf < 4; ++mf)
#pragma unroll
            for (int nf = 0; nf < 4; ++nf) {
                const int c = wn + nf * 16 + l16;
#pragma unroll
                for (int reg = 0; reg < 4; ++reg) {
                    const int s = wm + mf * 16 + quad * 4 + reg;
                    T[s * 128 + (((c >> 3) ^ (s & 15)) << 3) + (c & 7)] =
                        f2bf(acc[mf][nf][reg] * inv[mf][reg]);
                }
            }
        __syncthreads();
        short* outp = (mat == 0) ? qws : kws;
        const int r = t >> 1, half = t & 1;
        const int sg = m0 + r, bb = sg >> 11, sl = sg & (SEQ - 1);
        const int h = ((n0 & 1023) >> 6) + half;
        short* obase = outp + ((size_t)(bb * NH + h) * 128 + (sl >> 4)) * 1024;
#pragma unroll
        for (int j = 0; j < 8; ++j) {
            int4 v = *(const int4*)&T[r * 128 + (((half * 8 + j) ^ (r & 15)) << 3)];
            *(int4*)&obase[(j >> 2) * 512 + ((j & 3) * 16 + (sl & 15)) * 8] = v;
        }
    } else {
        // V: T at plain token rows; readback gathers slot->token into frag blocks
#pragma unroll
        for (int mf = 0; mf < 4; ++mf)
#pragma unroll
            for (int nf = 0; nf < 4; ++nf) {
                const int c = wn + nf * 16 + l16;
#pragma unroll
                for (int reg = 0; reg < 4; ++reg) {
                    const int s = wm + mf * 16 + quad * 4 + reg;
                    T[s * 128 + (((c >> 3) ^ (s & 15)) << 3) + (c & 7)] =
                        f2bf(acc[mf][nf][reg]);
                }
            }
        __syncthreads();
        const int c = t >> 1, half = t & 1;
        const int h = ((n0 & 1023) >> 6) + (c >> 6), d = c & 63;
        const int nt = d >> 4, l16v = d & 15;
        const int bb = m0 >> 11, sl0 = m0 & (SEQ - 1);
        const int cg = c >> 3, ce = c & 7;
#pragma unroll
        for (int ss = 0; ss < 2; ++ss) {
            const int strip = (sl0 >> 5) + half * 2 + ss;
            short* vb = vperm + (((size_t)(bb * NH + h) * 64 + strip) * 4 + nt) * 512;
#pragma unroll
            for (int q = 0; q < 4; ++q) {
                union { int4 v; short s[8]; } tmp;
#pragma unroll
                for (int jj = 0; jj < 8; ++jj) {
                    const int tl = (jj & 3) | (((jj >> 2) & 1) << 4) | (q << 2);
                    const int row = half * 64 + ss * 32 + tl;
                    tmp.s[jj] = T[row * 128 + ((cg ^ (row & 15)) << 3) + ce];
                }
                *(int4*)&vb[(q * 16 + l16v) * 8] = tmp.v;
            }
        }
    }
}

// ---------------------------------------------------------------------------
// Attention (wave-specialized over keys, 64-q blocks). All staging now
// fragment-order: contiguous 1KB gload16, contiguous conflict-free b128
// frag reads, coalesced Q register loads. Compute path unchanged from R9:
// S^T trick, ones-MFMA l, raw v_exp_f32, truncating pack, cross-kh LDS
// reduction. Grid 1024; bh = (id&7)*4 + ((id>>3)&3) for XCD K/V locality.
// ---------------------------------------------------------------------------
__global__ __launch_bounds__(256, 4) void attn_kernel(
    const short* __restrict__ qws, const short* __restrict__ kws,
    const short* __restrict__ vperm, float* __restrict__ out)
{
    __shared__ short Kt[2][2][2048];   // [buf][kh][4 frag blocks]
    __shared__ short Vt[2][2][2048];   // [buf][kh][4 frag blocks]
    __shared__ float lbuf[64];

    const int id = blockIdx.x;
    const int bh = (id & 7) * 4 + ((id >> 3) & 3);
    const int qt = id >> 5;                        // 0..31
    const int b = bh >> 4, h = bh & (NH - 1);
    const int t = threadIdx.x, wave = t >> 6, lane = t & 63;
    const int quad = lane >> 4, l16 = lane & 15;
    const int qh = wave >> 1, kh = wave & 1;

    // Q B-frags: contiguous frag-block loads
    bf16x8 bq[2][2];
#pragma unroll
    for (int qsub = 0; qsub < 2; ++qsub) {
        const short* qp = qws +
            ((size_t)bh * 128 + qt * 4 + qh * 2 + qsub) * 1024 + lane * 8;
        bq[qsub][0] = *(const bf16x8*)(qp);
        bq[qsub][1] = *(const bf16x8*)(qp + 512);
    }
    bf16x8 ones;
#pragma unroll
    for (int i = 0; i < 8; ++i) ones[i] = (short)0x3F80;

    f32x4 o_acc[2][4] = {};   // [qsub][nt]
    f32x4 l_acc[2] = {};

    // stage tile tt (this wave's kh strip) into buffer p — all contiguous
    auto stage = [&](int tt, int p) {
        if (qh == 0) {  // K: 2 strips x 2 ks
            const size_t kb = (size_t)bh * 128 + tt * 4 + kh * 2;
#pragma unroll
            for (int s = 0; s < 2; ++s)
#pragma unroll
                for (int ks = 0; ks < 2; ++ks)
                    gload16(kws + ((kb + s) * 2 + ks) * 512 + lane * 8,
                            &Kt[p][kh][(s * 2 + ks) * 512 + lane * 8]);
        } else {        // V: 4 nt blocks of this 32-key strip
            const size_t vb = ((size_t)bh * 64 + tt * 2 + kh) * 4;
#pragma unroll
            for (int nt = 0; nt < 4; ++nt)
                gload16(vperm + (vb + nt) * 512 + lane * 8,
                        &Vt[p][kh][nt * 512 + lane * 8]);
        }
    };

    stage(0, 0);
    __syncthreads();   // tile 0 resident

    for (int tt = 0; tt < SEQ / 64; ++tt) {
        const int p = tt & 1;
        if (tt + 1 < SEQ / 64) stage(tt + 1, p ^ 1);   // prefetch overlaps compute
        const short* Kp = &Kt[p][kh][0];
        const short* Vp = &Vt[p][kh][0];

        // S^T: 32 keys (this strip) x 32 q (this half)
        f32x4 st[2][2];   // [msub][qsub]
#pragma unroll
        for (int msub = 0; msub < 2; ++msub) {
            bf16x8 a0 = *(const bf16x8*)(Kp + (msub * 2 + 0) * 512 + lane * 8);
            bf16x8 a1 = *(const bf16x8*)(Kp + (msub * 2 + 1) * 512 + lane * 8);
#pragma unroll
            for (int qsub = 0; qsub < 2; ++qsub) {
                f32x4 z = {};
                z = MFMA16(a0, bq[qsub][0], z);
                st[msub][qsub] = MFMA16(a1, bq[qsub][1], z);
            }
        }
        // V B-frags (shared across qsub)
        bf16x8 vf[4];
#pragma unroll
        for (int nt = 0; nt < 4; ++nt)
            vf[nt] = *(const bf16x8*)(Vp + nt * 512 + lane * 8);
        // exp + truncating pack -> P A-frag; l + O MFMAs
#pragma unroll
        for (int qsub = 0; qsub < 2; ++qsub) {
            bf16x8 pa;
            unsigned* pu = (unsigned*)&pa;
            pu[0] = pack2bf_t(fast_exp2(st[0][qsub][0]), fast_exp2(st[0][qsub][1]));
            pu[1] = pack2bf_t(fast_exp2(st[0][qsub][2]), fast_exp2(st[0][qsub][3]));
            pu[2] = pack2bf_t(fast_exp2(st[1][qsub][0]), fast_exp2(st[1][qsub][1]));
            pu[3] = pack2bf_t(fast_exp2(st[1][qsub][2]), fast_exp2(st[1][qsub][3]));
            l_acc[qsub] = MFMA16(pa, ones, l_acc[qsub]);
#pragma unroll
            for (int nt = 0; nt < 4; ++nt)
                o_acc[qsub][nt] = MFMA16(pa, vf[nt], o_acc[qsub][nt]);
        }
        __syncthreads();   // drains prefetch (after compute) + guards buffer reuse
    }

    // ---- cross-kh reduction (reuse Kt as 16 KB float buffer) ----
    float* red = (float*)&Kt[0][0][0];   // [qh][q_local 32][d 64]
    if (kh == 1) {
#pragma unroll
        for (int qsub = 0; qsub < 2; ++qsub) {
#pragma unroll
            for (int nt = 0; nt < 4; ++nt)
#pragma unroll
                for (int r = 0; r < 4; ++r)
                    red[qh * 2048 + (qsub * 16 + quad * 4 + r) * 64 + nt * 16 + l16] =
                        o_acc[qsub][nt][r];
            if (l16 == 0)
#pragma unroll
                for (int r = 0; r < 4; ++r)
                    lbuf[qh * 32 + qsub * 16 + quad * 4 + r] = l_acc[qsub][r];
        }
    }
    __syncthreads();
    if (kh == 0) {
#pragma unroll
        for (int qsub = 0; qsub < 2; ++qsub) {
            float linv[4];
#pragma unroll
            for (int r = 0; r < 4; ++r)
                linv[r] = 1.0f / (l_acc[qsub][r] + lbuf[qh * 32 + qsub * 16 + quad * 4 + r]);
            const int s = qt * 64 + qh * 32 + qsub * 16 + quad * 4;
            float* ob = out + ((size_t)b * SEQ + s) * EMB + h * HD + l16;
#pragma unroll
            for (int nt = 0; nt < 4; ++nt)
#pragma unroll
                for (int r = 0; r < 4; ++r) {
                    const float o = o_acc[qsub][nt][r] +
                        red[qh * 2048 + (qsub * 16 + quad * 4 + r) * 64 + nt * 16 + l16];
                    ob[(size_t)r * EMB + nt * 16] = o * linv[r];
                }
        }
    }
}

extern "C" void kernel_launch(void* const* d_in, const int* in_sizes, int n_in,
                              void* d_out, int out_size, void* d_ws, size_t ws_size,
                              hipStream_t stream) {
    (void)in_sizes; (void)n_in; (void)out_size; (void)ws_size;
    const float* x  = (const float*)d_in[0];
    const float* Wq = (const float*)d_in[1];
    const float* Wk = (const float*)d_in[2];
    const float* Wv = (const float*)d_in[3];
    const float* g  = (const float*)d_in[4];
    float* out = (float*)d_out;

    const size_t per = (size_t)BAT * NH * SEQ * HD;   // 4,194,304 elems
    short* qws   = (short*)d_ws;
    short* kws   = qws + per;
    short* vperm = kws + per;                          // ws: 25.2 MB total

    // bf16 staging lives in d_out (16.8 MB; attn fully overwrites it last)
    short* xb = (short*)out;                           // 4M shorts
    short* wb = xb + (size_t)MTOT * EMB;               // 3M shorts (7M <= 8.38M cap)

    prep_kernel<<<3584, 256, 0, stream>>>(x, Wq, Wk, Wv, xb, wb);
    qkv_gemm_fast<<<dim3(MTOT / 128, NTOT / 128), 256, 0, stream>>>(
        xb, wb, qws, kws, vperm, g);
    attn_kernel<<<(SEQ / 64) * BAT * NH, 256, 0, stream>>>(qws, kws, vperm, out);
}